// Round 5
// baseline (417.105 us; speedup 1.0000x reference)
//
#include <hip/hip_runtime.h>
#include <hip/hip_bf16.h>

typedef __attribute__((ext_vector_type(8))) short short8;
typedef __attribute__((ext_vector_type(4))) float floatx4;

#define B_    4
#define S_    2048
#define EMB_  1024
#define NH_   16
#define HD_   64

#if __has_builtin(__builtin_amdgcn_exp2f)
#define EXP2F(x) __builtin_amdgcn_exp2f(x)
#else
#define EXP2F(x) exp2f(x)
#endif

__device__ __forceinline__ void async_cp16(const void* g, void* l) {
  __builtin_amdgcn_global_load_lds(
      (const __attribute__((address_space(1))) unsigned int*)g,
      (__attribute__((address_space(3))) unsigned int*)l, 16, 0, 0);
}

__device__ __forceinline__ ushort4 cvt4(const float4 f) {
  __bf16 t[4] = {(__bf16)f.x, (__bf16)f.y, (__bf16)f.z, (__bf16)f.w};
  return *(const ushort4*)t;
}

// One-shot fp32 -> bf16 conversion of x, Wq|Wk|Wv (stacked into Wcat), Wo,
// plus fp32 bias packing bq|bk|bv -> bcat. 4 elems/thread.
__global__ __launch_bounds__(256)
void cvt_kernel(const float* __restrict__ x,
                const float* __restrict__ wq, const float* __restrict__ wk,
                const float* __restrict__ wv, const float* __restrict__ wo,
                const float* __restrict__ bq, const float* __restrict__ bk,
                const float* __restrict__ bv,
                __bf16* __restrict__ xb, __bf16* __restrict__ Wcat,
                __bf16* __restrict__ Wob, float* __restrict__ bcat)
{
  const int NX4 = 2097152;   // 8388608/4
  const int NW4 = 262144;    // 1048576/4
  int g = blockIdx.x * 256 + threadIdx.x;
  if (g < NX4) {
    *(ushort4*)(xb + (size_t)g * 4) = cvt4(*(const float4*)(x + (size_t)g * 4));
    return;
  }
  g -= NX4;
  if (g < 3 * NW4) {   // Wcat = [Wq; Wk; Wv] row-stacked
    const float* src = (g < NW4) ? wq : (g < 2 * NW4) ? wk : wv;
    const int gg = (g < NW4) ? g : (g < 2 * NW4) ? g - NW4 : g - 2 * NW4;
    *(ushort4*)(Wcat + (size_t)g * 4) = cvt4(*(const float4*)(src + (size_t)gg * 4));
    return;
  }
  g -= 3 * NW4;
  if (g < NW4) {
    *(ushort4*)(Wob + (size_t)g * 4) = cvt4(*(const float4*)(wo + (size_t)g * 4));
    return;
  }
  g -= NW4;
  if (g < 768) {       // bcat = [bq; bk; bv] fp32
    const float* src = (g < 256) ? bq : (g < 512) ? bk : bv;
    *(float4*)(bcat + (size_t)g * 4) = *(const float4*)(src + (size_t)(g & 255) * 4);
  }
}

// Fused QKV: C[8192,3072] = xb @ Wcat^T + bcat, all bf16, global_load_lds staging.
// n<1024 -> Q (scaled by SCL*log2e) BHSD; n<2048 -> K BHSD; else -> V^T BHDS.
__global__ __launch_bounds__(256)
void gemm_qkv_kernel(const __bf16* __restrict__ A, const __bf16* __restrict__ W,
                     const float* __restrict__ bcat,
                     __bf16* __restrict__ Qb, __bf16* __restrict__ Kb,
                     __bf16* __restrict__ Vb)
{
  __shared__ __attribute__((aligned(16))) __bf16 As[128 * 32];
  __shared__ __attribute__((aligned(16))) __bf16 Ws[128 * 32];
  const int tid  = threadIdx.x;
  const int wave = tid >> 6, lane = tid & 63;
  const int l15  = lane & 15, quad = lane >> 4;
  const int wm   = wave >> 1, wn = wave & 1;
  const int bm   = blockIdx.y * 128;
  const int bn   = blockIdx.x * 128;        // 0..2944
  const int widx = bn >> 10;                // 0=Q 1=K 2=V (block-uniform)
  const float QS = 0.180336880f;            // (1/sqrt(64)) * log2(e)

  floatx4 acc[4][4];
#pragma unroll
  for (int i = 0; i < 4; ++i)
#pragma unroll
    for (int j = 0; j < 4; ++j) acc[i][j] = (floatx4){0.f, 0.f, 0.f, 0.f};

  const int srow = tid >> 2;          // 0..63
  const int scol = (tid & 3) << 3;    // 0,8,16,24
  const __bf16* Ag = A + (size_t)(bm + srow) * 1024 + scol;
  const __bf16* Wg = W + (size_t)(bn + srow) * 1024 + scol;
  __bf16* AsD = As + tid * 8;
  __bf16* WsD = Ws + tid * 8;

  for (int k0 = 0; k0 < 1024; k0 += 32) {
    __syncthreads();
    async_cp16(Ag + k0,             AsD);
    async_cp16(Ag + k0 + 64 * 1024, AsD + 2048);
    async_cp16(Wg + k0,             WsD);
    async_cp16(Wg + k0 + 64 * 1024, WsD + 2048);
    __syncthreads();
    short8 af[4], wf[4];
#pragma unroll
    for (int mi = 0; mi < 4; ++mi)
      af[mi] = *(const short8*)(As + ((wm * 64 + mi * 16 + l15) << 5) + (quad << 3));
#pragma unroll
    for (int ni = 0; ni < 4; ++ni)
      wf[ni] = *(const short8*)(Ws + ((wn * 64 + ni * 16 + l15) << 5) + (quad << 3));
#pragma unroll
    for (int mi = 0; mi < 4; ++mi)
#pragma unroll
      for (int ni = 0; ni < 4; ++ni)
        acc[mi][ni] = __builtin_amdgcn_mfma_f32_16x16x32_bf16(af[mi], wf[ni], acc[mi][ni], 0, 0, 0);
  }

#pragma unroll
  for (int ni = 0; ni < 4; ++ni) {
    const int n  = bn + wn * 64 + ni * 16 + l15;
    const float bvb = bcat[n];
    const int np = n & 1023;
    const int h = np >> 6, d = np & 63;
#pragma unroll
    for (int mi = 0; mi < 4; ++mi) {
      const int m0 = bm + wm * 64 + mi * 16 + quad * 4;
      const int b = m0 >> 11, s0 = m0 & 2047;
      floatx4 v = acc[mi][ni];
      if (widx == 0) {
        const size_t base = (size_t)(b * 16 + h) * (S_ * 64) + d;
#pragma unroll
        for (int r = 0; r < 4; ++r)
          Qb[base + (size_t)(s0 + r) * 64] = (__bf16)((v[r] + bvb) * QS);
      } else if (widx == 1) {
        const size_t base = (size_t)(b * 16 + h) * (S_ * 64) + d;
#pragma unroll
        for (int r = 0; r < 4; ++r)
          Kb[base + (size_t)(s0 + r) * 64] = (__bf16)(v[r] + bvb);
      } else {
        const size_t base = ((size_t)(b * 16 + h) * 64 + d) * S_ + s0;
        union { ushort4 u4; unsigned short u[4]; } pk;
#pragma unroll
        for (int r = 0; r < 4; ++r) {
          __bf16 hv = (__bf16)(v[r] + bvb);
          pk.u[r] = *(unsigned short*)&hv;
        }
        *(ushort4*)(Vb + base) = pk.u4;    // 8B aligned: s0 % 4 == 0
      }
    }
  }
}

// Flash attention, causal, exp2-domain (Q pre-scaled by SCL*log2e).
// Round-2 16x16 engine (proven 86 us) with KVBLK=128: each staged region holds
// TWO 64-kv sub-tiles -> barrier pairs per block drop 33 -> ~17, staging
// latency exposure halves, T14 prefetch distance doubles (128 rows in flight).
// Grid (16, 64): block serially processes paired q-tiles {qtA, 31-qtA}.
// SWAPPED OPERANDS: S^T = mfma(K, Q), lane owns q-row = l15; lane-local
// softmax (15 fmax + 2 shfl); T13 defer-max; P -> per-wave Ps (wave-local
// lgkm drain, no block barrier); PV: O^T = mfma(V^T, P^T).
// LDS 44 KB -> 3 blocks/CU; VGPR ~110 under the (256,3) cap of 170.
// Output IN-PLACE over Q (block-owned rows).
__global__ __launch_bounds__(256, 3)
void attn_kernel(__bf16* __restrict__ Q, const __bf16* __restrict__ K,
                 const __bf16* __restrict__ Vt)
{
  __shared__ __attribute__((aligned(16))) __bf16 Ks[128 * 72];   // [kv][d]
  __shared__ __attribute__((aligned(16))) __bf16 Vs[64 * 136];   // [d][kv]
  __shared__ __attribute__((aligned(16))) __bf16 Ps[4][16 * 72];

  const int tid  = threadIdx.x;
  const int wave = tid >> 6, lane = tid & 63;
  const int l15  = lane & 15, quad = lane >> 4;
  const int qtA  = blockIdx.x, bh = blockIdx.y;
  const size_t hb = (size_t)bh * (S_ * 64);
  const float MASKV = -1.0e30f;

  // staging decomposition: K tile 128x64 (contiguous 16 KB), V^T tile 64x128
  const int srow = tid >> 3;          // 0..31  (K rows, +u*32)
  const int scol = (tid & 7) << 3;    // 0..56  (K d-chunk)
  const int vrow = tid >> 2;          // 0..63  (V^T d-row)
  const int vcol = (tid & 3) << 5;    // 0,32,64,96 (V^T kv-chunk base, +u*8)

  for (int qsel = 0; qsel < 2; ++qsel) {
    const int qt = qsel ? (31 - qtA) : qtA;
    const int qw = qt * 64 + wave * 16;     // wave's first q row
    const int myq = qw + l15;               // this lane's q row
    const int nkt = (qt >> 1) + 1;          // number of 128-row kv blocks

    // Q fragments in registers: B-operand view Q^T[c][q]: lane q = l15
    short8 aq[2];
#pragma unroll
    for (int kk = 0; kk < 2; ++kk)
      aq[kk] = *(const short8*)(Q + hb + (size_t)myq * 64 + kk * 32 + quad * 8);

    floatx4 oacc[4];                        // O^T: d = ni*16+quad*4+r, q = l15
#pragma unroll
    for (int j = 0; j < 4; ++j) oacc[j] = (floatx4){0.f, 0.f, 0.f, 0.f};
    float lsum = 0.0f;
    float mrun = MASKV;

    // prologue: issue ktt=0 tile loads into regs (T14 issue-early)
    uint4 kreg[4], vreg[4];
    {
      const __bf16* kp = K  + hb + (size_t)srow * 64 + scol;
      const __bf16* vp = Vt + hb + (size_t)vrow * S_ + vcol;
#pragma unroll
      for (int u = 0; u < 4; ++u) {
        kreg[u] = *(const uint4*)(kp + (size_t)u * 32 * 64);   // rows srow+u*32
        vreg[u] = *(const uint4*)(vp + u * 8);                 // cols vcol+u*8
      }
    }

    for (int ktt = 0; ktt < nkt; ++ktt) {
      __syncthreads();                      // all waves done reading prev tile
#pragma unroll
      for (int u = 0; u < 4; ++u) {
        *(uint4*)(&Ks[(srow + u * 32) * 72 + scol]) = kreg[u];
        *(uint4*)(&Vs[vrow * 136 + vcol + u * 8])   = vreg[u];
      }
      __syncthreads();                      // tile staged

      if (ktt + 1 < nkt) {                  // prefetch next 128-kv block
        const __bf16* kp = K  + hb + (size_t)((ktt + 1) * 128 + srow) * 64 + scol;
        const __bf16* vp = Vt + hb + (size_t)vrow * S_ + (ktt + 1) * 128 + vcol;
#pragma unroll
        for (int u = 0; u < 4; ++u) {
          kreg[u] = *(const uint4*)(kp + (size_t)u * 32 * 64);
          vreg[u] = *(const uint4*)(vp + u * 8);
        }
      }

#pragma unroll
      for (int s2 = 0; s2 < 2; ++s2) {
        const int ksub = ktt * 2 + s2;      // 64-kv sub-tile index
        if (ksub <= qt) {
          // S^T = K Q^T: A-frag = K rows (k-local), B-frag = Q^T (q = l15)
          floatx4 sacc[4];
#pragma unroll
          for (int j = 0; j < 4; ++j) sacc[j] = (floatx4){0.f, 0.f, 0.f, 0.f};
#pragma unroll
          for (int kk = 0; kk < 2; ++kk) {
            short8 bk[4];
#pragma unroll
            for (int ni = 0; ni < 4; ++ni)
              bk[ni] = *(const short8*)(&Ks[(s2 * 64 + ni * 16 + l15) * 72 + kk * 32 + quad * 8]);
#pragma unroll
            for (int ni = 0; ni < 4; ++ni)
              sacc[ni] = __builtin_amdgcn_mfma_f32_16x16x32_bf16(bk[ni], aq[kk], sacc[ni], 0, 0, 0);
          }

          // causal mask (diagonal sub-tile only): k_global > q -> MASKV
          if (ksub == qt) {
            const int kb = ksub * 64 + quad * 4;
#pragma unroll
            for (int ni = 0; ni < 4; ++ni)
#pragma unroll
              for (int r = 0; r < 4; ++r)
                if (kb + ni * 16 + r > myq) sacc[ni][r] = MASKV;
          }

          // lane-local max over 16 k-values, then cross-quad reduce
          float t0 = fmaxf(fmaxf(sacc[0][0], sacc[0][1]), fmaxf(sacc[0][2], sacc[0][3]));
          float t1 = fmaxf(fmaxf(sacc[1][0], sacc[1][1]), fmaxf(sacc[1][2], sacc[1][3]));
          float t2 = fmaxf(fmaxf(sacc[2][0], sacc[2][1]), fmaxf(sacc[2][2], sacc[2][3]));
          float t3 = fmaxf(fmaxf(sacc[3][0], sacc[3][1]), fmaxf(sacc[3][2], sacc[3][3]));
          float tmax = fmaxf(fmaxf(t0, t1), fmaxf(t2, t3));
          tmax = fmaxf(tmax, __shfl_xor(tmax, 16));
          tmax = fmaxf(tmax, __shfl_xor(tmax, 32));

          const float mold = mrun;
          if (!__all(tmax <= mold + 8.0f)) {   // T13 defer-max
            const float mnew = fmaxf(mold, tmax);
            const float alpha = EXP2F(mold - mnew);
#pragma unroll
            for (int ni = 0; ni < 4; ++ni)
#pragma unroll
              for (int r = 0; r < 4; ++r) oacc[ni][r] *= alpha;
            lsum *= alpha;
            mrun = mnew;
          }
          const float m = mrun;

          // P = exp2(S - m): 4x ds_write_b64 into per-wave Ps[q=l15][k]
          float psum = 0.f;
#pragma unroll
          for (int ni = 0; ni < 4; ++ni) {
            float4 p;
            p.x = EXP2F(sacc[ni][0] - m);
            p.y = EXP2F(sacc[ni][1] - m);
            p.z = EXP2F(sacc[ni][2] - m);
            p.w = EXP2F(sacc[ni][3] - m);
            psum += (p.x + p.y) + (p.z + p.w);
            *(ushort4*)(&Ps[wave][l15 * 72 + ni * 16 + quad * 4]) = cvt4(p);
          }
          lsum += psum;

          // Ps is per-wave: wave-local LDS drain instead of __syncthreads
          asm volatile("s_waitcnt lgkmcnt(0)" ::: "memory");
          __builtin_amdgcn_sched_barrier(0);

          // O^T += V^T P^T: A-frag = V^T rows (d-local), B-frag = P^T (q = l15)
#pragma unroll
          for (int kk = 0; kk < 2; ++kk) {
            const short8 pf = *(const short8*)(&Ps[wave][l15 * 72 + kk * 32 + quad * 8]);
            short8 bv[4];
#pragma unroll
            for (int ni = 0; ni < 4; ++ni)
              bv[ni] = *(const short8*)(&Vs[(ni * 16 + l15) * 136 + s2 * 64 + kk * 32 + quad * 8]);
#pragma unroll
            for (int ni = 0; ni < 4; ++ni)
              oacc[ni] = __builtin_amdgcn_mfma_f32_16x16x32_bf16(bv[ni], pf, oacc[ni], 0, 0, 0);
          }
        }
      }
    }

    // epilogue: l(q) = sum over 4 quads of lane-local partials
    float l = lsum;
    l += __shfl_xor(l, 16);
    l += __shfl_xor(l, 32);
    const float inv = 1.0f / fmaxf(l, 1e-20f);
    const size_t rowb = hb + (size_t)myq * 64;
#pragma unroll
    for (int ni = 0; ni < 4; ++ni) {
      float4 o;
      o.x = oacc[ni][0] * inv;
      o.y = oacc[ni][1] * inv;
      o.z = oacc[ni][2] * inv;
      o.w = oacc[ni][3] * inv;
      *(ushort4*)(Q + rowb + ni * 16 + quad * 4) = cvt4(o);  // 8B aligned
    }
  }
}

// Final projection: A = attn output (bf16, BHSD gather), W = Wob bf16,
// bias fp32, out fp32 row-major. global_load_lds staging.
__global__ __launch_bounds__(256)
void gemm_o_kernel(const __bf16* __restrict__ A, const __bf16* __restrict__ W,
                   const float* __restrict__ bias, float* __restrict__ out)
{
  __shared__ __attribute__((aligned(16))) __bf16 As[128 * 32];
  __shared__ __attribute__((aligned(16))) __bf16 Ws[128 * 32];
  const int tid  = threadIdx.x;
  const int wave = tid >> 6, lane = tid & 63;
  const int l15  = lane & 15, quad = lane >> 4;
  const int wm   = wave >> 1, wn = wave & 1;
  const int bm   = blockIdx.y * 128;
  const int bn   = blockIdx.x * 128;

  floatx4 acc[4][4];
#pragma unroll
  for (int i = 0; i < 4; ++i)
#pragma unroll
    for (int j = 0; j < 4; ++j) acc[i][j] = (floatx4){0.f, 0.f, 0.f, 0.f};

  const int srow = tid >> 2;
  const int scol = (tid & 3) << 3;
  const __bf16* Wg = W + (size_t)(bn + srow) * 1024 + scol;
  const int bb = bm >> 11;                 // batch
  const int ss = (bm & 2047) + srow;       // seq
  __bf16* AsD = As + tid * 8;
  __bf16* WsD = Ws + tid * 8;

  for (int k0 = 0; k0 < 1024; k0 += 32) {
    const int c = k0 + scol, h = c >> 6, dd = c & 63;  // 8 elems never cross a head
    const __bf16* pa0 = A + (((size_t)(bb * 16 + h) * S_) + ss) * 64 + dd;
    __syncthreads();
    async_cp16(pa0,           AsD);
    async_cp16(pa0 + 64 * 64, AsD + 2048);             // s -> s+64
    async_cp16(Wg + k0,             WsD);
    async_cp16(Wg + k0 + 64 * 1024, WsD + 2048);
    __syncthreads();

    short8 af[4], wf[4];
#pragma unroll
    for (int mi = 0; mi < 4; ++mi)
      af[mi] = *(const short8*)(As + ((wm * 64 + mi * 16 + l15) << 5) + (quad << 3));
#pragma unroll
    for (int ni = 0; ni < 4; ++ni)
      wf[ni] = *(const short8*)(Ws + ((wn * 64 + ni * 16 + l15) << 5) + (quad << 3));
#pragma unroll
    for (int mi = 0; mi < 4; ++mi)
#pragma unroll
      for (int ni = 0; ni < 4; ++ni)
        acc[mi][ni] = __builtin_amdgcn_mfma_f32_16x16x32_bf16(af[mi], wf[ni], acc[mi][ni], 0, 0, 0);
  }

#pragma unroll
  for (int ni = 0; ni < 4; ++ni) {
    const int n = bn + wn * 64 + ni * 16 + l15;
    const float bvb = bias[n];
#pragma unroll
    for (int mi = 0; mi < 4; ++mi) {
      const int m0 = bm + wm * 64 + mi * 16 + quad * 4;
      floatx4 v = acc[mi][ni];
#pragma unroll
      for (int r = 0; r < 4; ++r)
        out[(size_t)(m0 + r) * 1024 + n] = v[r] + bvb;
    }
  }
}

extern "C" void kernel_launch(void* const* d_in, const int* in_sizes, int n_in,
                              void* d_out, int out_size, void* d_ws, size_t ws_size,
                              hipStream_t stream) {
  const float* x  = (const float*)d_in[0];
  const float* Wq = (const float*)d_in[1];
  const float* bq = (const float*)d_in[2];
  const float* Wk = (const float*)d_in[3];
  const float* bk = (const float*)d_in[4];
  const float* Wv = (const float*)d_in[5];
  const float* bv = (const float*)d_in[6];
  const float* Wo = (const float*)d_in[7];
  const float* bo = (const float*)d_in[8];
  // d_in[9] = causal_mask (int32) — causality implemented analytically, unused.

  const size_t BUF = (size_t)B_ * NH_ * S_ * HD_;   // 8388608 elems
  __bf16* ws   = (__bf16*)d_ws;                     // ws usage: ~42 MB
  __bf16* xb   = ws;                                // 8388608  (16.8 MB)
  __bf16* Wcat = ws + 8388608;                      // 3145728  (6 MB)
  __bf16* Wob  = ws + 11534336;                     // 1048576  (2 MB)
  __bf16* Qb   = ws + 12582912;                     // 8388608  (16.8 MB)
  float*  bcat = (float*)(ws + 20971520);           // 3072 fp32 (12 KB)
  __bf16* Kb   = (__bf16*)d_out;                    // d_out reused as K+V^T
  __bf16* Vb   = (__bf16*)d_out + BUF;              // scratch until attn done

  dim3 blk(256);
  cvt_kernel<<<12291, blk, 0, stream>>>(x, Wq, Wk, Wv, Wo, bq, bk, bv,
                                        xb, Wcat, Wob, bcat);
  gemm_qkv_kernel<<<dim3(24, 64), blk, 0, stream>>>(xb, Wcat, bcat, Qb, Kb, Vb);
  attn_kernel<<<dim3(16, 64), blk, 0, stream>>>(Qb, Kb, Vb);
  gemm_o_kernel<<<dim3(8, 64), blk, 0, stream>>>(Qb, Wob, bo, (float*)d_out);
}

// Round 6
// 293.984 us; speedup vs baseline: 1.4188x; 1.4188x over previous
//
#include <hip/hip_runtime.h>
#include <hip/hip_bf16.h>

typedef __attribute__((ext_vector_type(8))) short short8;
typedef __attribute__((ext_vector_type(4))) float floatx4;

#define B_    4
#define S_    2048
#define EMB_  1024
#define NH_   16
#define HD_   64

#if __has_builtin(__builtin_amdgcn_exp2f)
#define EXP2F(x) __builtin_amdgcn_exp2f(x)
#else
#define EXP2F(x) exp2f(x)
#endif

__device__ __forceinline__ void async_cp16(const void* g, void* l) {
  __builtin_amdgcn_global_load_lds(
      (const __attribute__((address_space(1))) unsigned int*)g,
      (__attribute__((address_space(3))) unsigned int*)l, 16, 0, 0);
}

__device__ __forceinline__ ushort4 cvt4(const float4 f) {
  __bf16 t[4] = {(__bf16)f.x, (__bf16)f.y, (__bf16)f.z, (__bf16)f.w};
  return *(const ushort4*)t;
}

// One-shot fp32 -> bf16 conversion of x, Wq|Wk|Wv (stacked into Wcat), Wo,
// plus fp32 bias packing bq|bk|bv -> bcat. 4 elems/thread.
__global__ __launch_bounds__(256)
void cvt_kernel(const float* __restrict__ x,
                const float* __restrict__ wq, const float* __restrict__ wk,
                const float* __restrict__ wv, const float* __restrict__ wo,
                const float* __restrict__ bq, const float* __restrict__ bk,
                const float* __restrict__ bv,
                __bf16* __restrict__ xb, __bf16* __restrict__ Wcat,
                __bf16* __restrict__ Wob, float* __restrict__ bcat)
{
  const int NX4 = 2097152;   // 8388608/4
  const int NW4 = 262144;    // 1048576/4
  int g = blockIdx.x * 256 + threadIdx.x;
  if (g < NX4) {
    *(ushort4*)(xb + (size_t)g * 4) = cvt4(*(const float4*)(x + (size_t)g * 4));
    return;
  }
  g -= NX4;
  if (g < 3 * NW4) {   // Wcat = [Wq; Wk; Wv] row-stacked
    const float* src = (g < NW4) ? wq : (g < 2 * NW4) ? wk : wv;
    const int gg = (g < NW4) ? g : (g < 2 * NW4) ? g - NW4 : g - 2 * NW4;
    *(ushort4*)(Wcat + (size_t)g * 4) = cvt4(*(const float4*)(src + (size_t)gg * 4));
    return;
  }
  g -= 3 * NW4;
  if (g < NW4) {
    *(ushort4*)(Wob + (size_t)g * 4) = cvt4(*(const float4*)(wo + (size_t)g * 4));
    return;
  }
  g -= NW4;
  if (g < 768) {       // bcat = [bq; bk; bv] fp32
    const float* src = (g < 256) ? bq : (g < 512) ? bk : bv;
    *(float4*)(bcat + (size_t)g * 4) = *(const float4*)(src + (size_t)(g & 255) * 4);
  }
}

// Fused QKV: C[8192,3072] = xb @ Wcat^T + bcat, all bf16, global_load_lds staging.
// n<1024 -> Q (scaled by SCL*log2e) BHSD; n<2048 -> K BHSD; else -> V^T BHDS.
__global__ __launch_bounds__(256)
void gemm_qkv_kernel(const __bf16* __restrict__ A, const __bf16* __restrict__ W,
                     const float* __restrict__ bcat,
                     __bf16* __restrict__ Qb, __bf16* __restrict__ Kb,
                     __bf16* __restrict__ Vb)
{
  __shared__ __attribute__((aligned(16))) __bf16 As[128 * 32];
  __shared__ __attribute__((aligned(16))) __bf16 Ws[128 * 32];
  const int tid  = threadIdx.x;
  const int wave = tid >> 6, lane = tid & 63;
  const int l15  = lane & 15, quad = lane >> 4;
  const int wm   = wave >> 1, wn = wave & 1;
  const int bm   = blockIdx.y * 128;
  const int bn   = blockIdx.x * 128;        // 0..2944
  const int widx = bn >> 10;                // 0=Q 1=K 2=V (block-uniform)
  const float QS = 0.180336880f;            // (1/sqrt(64)) * log2(e)

  floatx4 acc[4][4];
#pragma unroll
  for (int i = 0; i < 4; ++i)
#pragma unroll
    for (int j = 0; j < 4; ++j) acc[i][j] = (floatx4){0.f, 0.f, 0.f, 0.f};

  const int srow = tid >> 2;          // 0..63
  const int scol = (tid & 3) << 3;    // 0,8,16,24
  const __bf16* Ag = A + (size_t)(bm + srow) * 1024 + scol;
  const __bf16* Wg = W + (size_t)(bn + srow) * 1024 + scol;
  __bf16* AsD = As + tid * 8;
  __bf16* WsD = Ws + tid * 8;

  for (int k0 = 0; k0 < 1024; k0 += 32) {
    __syncthreads();
    async_cp16(Ag + k0,             AsD);
    async_cp16(Ag + k0 + 64 * 1024, AsD + 2048);
    async_cp16(Wg + k0,             WsD);
    async_cp16(Wg + k0 + 64 * 1024, WsD + 2048);
    __syncthreads();
    short8 af[4], wf[4];
#pragma unroll
    for (int mi = 0; mi < 4; ++mi)
      af[mi] = *(const short8*)(As + ((wm * 64 + mi * 16 + l15) << 5) + (quad << 3));
#pragma unroll
    for (int ni = 0; ni < 4; ++ni)
      wf[ni] = *(const short8*)(Ws + ((wn * 64 + ni * 16 + l15) << 5) + (quad << 3));
#pragma unroll
    for (int mi = 0; mi < 4; ++mi)
#pragma unroll
      for (int ni = 0; ni < 4; ++ni)
        acc[mi][ni] = __builtin_amdgcn_mfma_f32_16x16x32_bf16(af[mi], wf[ni], acc[mi][ni], 0, 0, 0);
  }

#pragma unroll
  for (int ni = 0; ni < 4; ++ni) {
    const int n  = bn + wn * 64 + ni * 16 + l15;
    const float bvb = bcat[n];
    const int np = n & 1023;
    const int h = np >> 6, d = np & 63;
#pragma unroll
    for (int mi = 0; mi < 4; ++mi) {
      const int m0 = bm + wm * 64 + mi * 16 + quad * 4;
      const int b = m0 >> 11, s0 = m0 & 2047;
      floatx4 v = acc[mi][ni];
      if (widx == 0) {
        const size_t base = (size_t)(b * 16 + h) * (S_ * 64) + d;
#pragma unroll
        for (int r = 0; r < 4; ++r)
          Qb[base + (size_t)(s0 + r) * 64] = (__bf16)((v[r] + bvb) * QS);
      } else if (widx == 1) {
        const size_t base = (size_t)(b * 16 + h) * (S_ * 64) + d;
#pragma unroll
        for (int r = 0; r < 4; ++r)
          Kb[base + (size_t)(s0 + r) * 64] = (__bf16)(v[r] + bvb);
      } else {
        const size_t base = ((size_t)(b * 16 + h) * 64 + d) * S_ + s0;
        union { ushort4 u4; unsigned short u[4]; } pk;
#pragma unroll
        for (int r = 0; r < 4; ++r) {
          __bf16 hv = (__bf16)(v[r] + bvb);
          pk.u[r] = *(unsigned short*)&hv;
        }
        *(ushort4*)(Vb + base) = pk.u4;    // 8B aligned: s0 % 4 == 0
      }
    }
  }
}

// Flash attention, causal, exp2-domain (Q pre-scaled by SCL*log2e).
// Round-2 16x16 engine with KVBLK=128 staging: each staged region holds TWO
// 64-kv sub-tiles -> barrier pairs per block drop 33 -> ~17.5, halving exposed
// staging latency; T14 prefetch distance doubles (128 rows in flight).
// SPILL FIX vs rounds 4/5: prefetch held in NAMED scalar uint4 (kreg0..3,
// vreg0..3) -- uint4 ARRAYS defeated SROA and produced ~500 MB scratch traffic
// (WRITE_SIZE counter) in both array-based variants.
// Grid (16, 64): block serially processes paired q-tiles {qtA, 31-qtA}.
// SWAPPED OPERANDS: S^T = mfma(K, Q), lane owns q-row = l15; lane-local
// softmax (15 fmax + 2 shfl); T13 defer-max; P -> per-wave Ps (wave-local
// lgkm drain, no block barrier); PV: O^T = mfma(V^T, P^T).
// LDS 44 KB -> 3 blocks/CU; VGPR ~110 under the (256,3) cap of 170.
// Output IN-PLACE over Q (block-owned rows).
__global__ __launch_bounds__(256, 3)
void attn_kernel(__bf16* __restrict__ Q, const __bf16* __restrict__ K,
                 const __bf16* __restrict__ Vt)
{
  __shared__ __attribute__((aligned(16))) __bf16 Ks[128 * 72];   // [kv][d]
  __shared__ __attribute__((aligned(16))) __bf16 Vs[64 * 136];   // [d][kv]
  __shared__ __attribute__((aligned(16))) __bf16 Ps[4][16 * 72];

  const int tid  = threadIdx.x;
  const int wave = tid >> 6, lane = tid & 63;
  const int l15  = lane & 15, quad = lane >> 4;
  const int qtA  = blockIdx.x, bh = blockIdx.y;
  const size_t hb = (size_t)bh * (S_ * 64);
  const float MASKV = -1.0e30f;

  // staging decomposition: K tile 128x64 (rows srow+u*32), V^T tile 64x128
  const int srow = tid >> 3;          // 0..31  (K rows)
  const int scol = (tid & 7) << 3;    // 0..56  (K d-chunk)
  const int vrow = tid >> 2;          // 0..63  (V^T d-row)
  const int vcol = (tid & 3) << 5;    // 0,32,64,96 (V^T kv-chunk base, +u*8)

  for (int qsel = 0; qsel < 2; ++qsel) {
    const int qt = qsel ? (31 - qtA) : qtA;
    const int qw = qt * 64 + wave * 16;     // wave's first q row
    const int myq = qw + l15;               // this lane's q row
    const int nkt = (qt >> 1) + 1;          // number of 128-row kv blocks

    // Q fragments in registers: B-operand view Q^T[c][q]: lane q = l15
    short8 aq0 = *(const short8*)(Q + hb + (size_t)myq * 64 + quad * 8);
    short8 aq1 = *(const short8*)(Q + hb + (size_t)myq * 64 + 32 + quad * 8);

    floatx4 oacc[4];                        // O^T: d = ni*16+quad*4+r, q = l15
#pragma unroll
    for (int j = 0; j < 4; ++j) oacc[j] = (floatx4){0.f, 0.f, 0.f, 0.f};
    float lsum = 0.0f;
    float mrun = MASKV;

    // prologue: issue ktt=0 tile loads into NAMED scalar regs (T14 issue-early)
    uint4 kreg0, kreg1, kreg2, kreg3, vreg0, vreg1, vreg2, vreg3;
    {
      const __bf16* kp = K  + hb + (size_t)srow * 64 + scol;
      const __bf16* vp = Vt + hb + (size_t)vrow * S_ + vcol;
      kreg0 = *(const uint4*)(kp);
      kreg1 = *(const uint4*)(kp + (size_t)32 * 64);
      kreg2 = *(const uint4*)(kp + (size_t)64 * 64);
      kreg3 = *(const uint4*)(kp + (size_t)96 * 64);
      vreg0 = *(const uint4*)(vp);
      vreg1 = *(const uint4*)(vp + 8);
      vreg2 = *(const uint4*)(vp + 16);
      vreg3 = *(const uint4*)(vp + 24);
    }

    for (int ktt = 0; ktt < nkt; ++ktt) {
      __syncthreads();                      // all waves done reading prev tile
      *(uint4*)(&Ks[(srow)      * 72 + scol]) = kreg0;
      *(uint4*)(&Ks[(srow + 32) * 72 + scol]) = kreg1;
      *(uint4*)(&Ks[(srow + 64) * 72 + scol]) = kreg2;
      *(uint4*)(&Ks[(srow + 96) * 72 + scol]) = kreg3;
      *(uint4*)(&Vs[vrow * 136 + vcol])      = vreg0;
      *(uint4*)(&Vs[vrow * 136 + vcol + 8])  = vreg1;
      *(uint4*)(&Vs[vrow * 136 + vcol + 16]) = vreg2;
      *(uint4*)(&Vs[vrow * 136 + vcol + 24]) = vreg3;
      __syncthreads();                      // tile staged

      if (ktt + 1 < nkt) {                  // prefetch next 128-kv block
        const __bf16* kp = K  + hb + (size_t)((ktt + 1) * 128 + srow) * 64 + scol;
        const __bf16* vp = Vt + hb + (size_t)vrow * S_ + (ktt + 1) * 128 + vcol;
        kreg0 = *(const uint4*)(kp);
        kreg1 = *(const uint4*)(kp + (size_t)32 * 64);
        kreg2 = *(const uint4*)(kp + (size_t)64 * 64);
        kreg3 = *(const uint4*)(kp + (size_t)96 * 64);
        vreg0 = *(const uint4*)(vp);
        vreg1 = *(const uint4*)(vp + 8);
        vreg2 = *(const uint4*)(vp + 16);
        vreg3 = *(const uint4*)(vp + 24);
      }

#pragma unroll
      for (int s2 = 0; s2 < 2; ++s2) {
        const int ksub = ktt * 2 + s2;      // 64-kv sub-tile index
        if (ksub <= qt) {
          // S^T = K Q^T: A-frag = K rows (k-local), B-frag = Q^T (q = l15)
          floatx4 sacc[4];
#pragma unroll
          for (int j = 0; j < 4; ++j) sacc[j] = (floatx4){0.f, 0.f, 0.f, 0.f};
#pragma unroll
          for (int kk = 0; kk < 2; ++kk) {
            const short8 aq = kk ? aq1 : aq0;
            short8 bk[4];
#pragma unroll
            for (int ni = 0; ni < 4; ++ni)
              bk[ni] = *(const short8*)(&Ks[(s2 * 64 + ni * 16 + l15) * 72 + kk * 32 + quad * 8]);
#pragma unroll
            for (int ni = 0; ni < 4; ++ni)
              sacc[ni] = __builtin_amdgcn_mfma_f32_16x16x32_bf16(bk[ni], aq, sacc[ni], 0, 0, 0);
          }

          // causal mask (diagonal sub-tile only): k_global > q -> MASKV
          if (ksub == qt) {
            const int kb = ksub * 64 + quad * 4;
#pragma unroll
            for (int ni = 0; ni < 4; ++ni)
#pragma unroll
              for (int r = 0; r < 4; ++r)
                if (kb + ni * 16 + r > myq) sacc[ni][r] = MASKV;
          }

          // lane-local max over 16 k-values, then cross-quad reduce
          float t0 = fmaxf(fmaxf(sacc[0][0], sacc[0][1]), fmaxf(sacc[0][2], sacc[0][3]));
          float t1 = fmaxf(fmaxf(sacc[1][0], sacc[1][1]), fmaxf(sacc[1][2], sacc[1][3]));
          float t2 = fmaxf(fmaxf(sacc[2][0], sacc[2][1]), fmaxf(sacc[2][2], sacc[2][3]));
          float t3 = fmaxf(fmaxf(sacc[3][0], sacc[3][1]), fmaxf(sacc[3][2], sacc[3][3]));
          float tmax = fmaxf(fmaxf(t0, t1), fmaxf(t2, t3));
          tmax = fmaxf(tmax, __shfl_xor(tmax, 16));
          tmax = fmaxf(tmax, __shfl_xor(tmax, 32));

          const float mold = mrun;
          if (!__all(tmax <= mold + 8.0f)) {   // T13 defer-max
            const float mnew = fmaxf(mold, tmax);
            const float alpha = EXP2F(mold - mnew);
#pragma unroll
            for (int ni = 0; ni < 4; ++ni)
#pragma unroll
              for (int r = 0; r < 4; ++r) oacc[ni][r] *= alpha;
            lsum *= alpha;
            mrun = mnew;
          }
          const float m = mrun;

          // P = exp2(S - m): 4x ds_write_b64 into per-wave Ps[q=l15][k]
          float psum = 0.f;
#pragma unroll
          for (int ni = 0; ni < 4; ++ni) {
            float4 p;
            p.x = EXP2F(sacc[ni][0] - m);
            p.y = EXP2F(sacc[ni][1] - m);
            p.z = EXP2F(sacc[ni][2] - m);
            p.w = EXP2F(sacc[ni][3] - m);
            psum += (p.x + p.y) + (p.z + p.w);
            *(ushort4*)(&Ps[wave][l15 * 72 + ni * 16 + quad * 4]) = cvt4(p);
          }
          lsum += psum;

          // Ps is per-wave: wave-local LDS drain instead of __syncthreads
          asm volatile("s_waitcnt lgkmcnt(0)" ::: "memory");
          __builtin_amdgcn_sched_barrier(0);

          // O^T += V^T P^T: A-frag = V^T rows (d-local), B-frag = P^T (q = l15)
#pragma unroll
          for (int kk = 0; kk < 2; ++kk) {
            const short8 pf = *(const short8*)(&Ps[wave][l15 * 72 + kk * 32 + quad * 8]);
            short8 bv[4];
#pragma unroll
            for (int ni = 0; ni < 4; ++ni)
              bv[ni] = *(const short8*)(&Vs[(ni * 16 + l15) * 136 + s2 * 64 + kk * 32 + quad * 8]);
#pragma unroll
            for (int ni = 0; ni < 4; ++ni)
              oacc[ni] = __builtin_amdgcn_mfma_f32_16x16x32_bf16(bv[ni], pf, oacc[ni], 0, 0, 0);
          }
        }
      }
    }

    // epilogue: l(q) = sum over 4 quads of lane-local partials
    float l = lsum;
    l += __shfl_xor(l, 16);
    l += __shfl_xor(l, 32);
    const float inv = 1.0f / fmaxf(l, 1e-20f);
    const size_t rowb = hb + (size_t)myq * 64;
#pragma unroll
    for (int ni = 0; ni < 4; ++ni) {
      float4 o;
      o.x = oacc[ni][0] * inv;
      o.y = oacc[ni][1] * inv;
      o.z = oacc[ni][2] * inv;
      o.w = oacc[ni][3] * inv;
      *(ushort4*)(Q + rowb + ni * 16 + quad * 4) = cvt4(o);  // 8B aligned
    }
  }
}

// Final projection: A = attn output (bf16, BHSD gather), W = Wob bf16,
// bias fp32, out fp32 row-major. global_load_lds staging.
__global__ __launch_bounds__(256)
void gemm_o_kernel(const __bf16* __restrict__ A, const __bf16* __restrict__ W,
                   const float* __restrict__ bias, float* __restrict__ out)
{
  __shared__ __attribute__((aligned(16))) __bf16 As[128 * 32];
  __shared__ __attribute__((aligned(16))) __bf16 Ws[128 * 32];
  const int tid  = threadIdx.x;
  const int wave = tid >> 6, lane = tid & 63;
  const int l15  = lane & 15, quad = lane >> 4;
  const int wm   = wave >> 1, wn = wave & 1;
  const int bm   = blockIdx.y * 128;
  const int bn   = blockIdx.x * 128;

  floatx4 acc[4][4];
#pragma unroll
  for (int i = 0; i < 4; ++i)
#pragma unroll
    for (int j = 0; j < 4; ++j) acc[i][j] = (floatx4){0.f, 0.f, 0.f, 0.f};

  const int srow = tid >> 2;
  const int scol = (tid & 3) << 3;
  const __bf16* Wg = W + (size_t)(bn + srow) * 1024 + scol;
  const int bb = bm >> 11;                 // batch
  const int ss = (bm & 2047) + srow;       // seq
  __bf16* AsD = As + tid * 8;
  __bf16* WsD = Ws + tid * 8;

  for (int k0 = 0; k0 < 1024; k0 += 32) {
    const int c = k0 + scol, h = c >> 6, dd = c & 63;  // 8 elems never cross a head
    const __bf16* pa0 = A + (((size_t)(bb * 16 + h) * S_) + ss) * 64 + dd;
    __syncthreads();
    async_cp16(pa0,           AsD);
    async_cp16(pa0 + 64 * 64, AsD + 2048);             // s -> s+64
    async_cp16(Wg + k0,             WsD);
    async_cp16(Wg + k0 + 64 * 1024, WsD + 2048);
    __syncthreads();

    short8 af[4], wf[4];
#pragma unroll
    for (int mi = 0; mi < 4; ++mi)
      af[mi] = *(const short8*)(As + ((wm * 64 + mi * 16 + l15) << 5) + (quad << 3));
#pragma unroll
    for (int ni = 0; ni < 4; ++ni)
      wf[ni] = *(const short8*)(Ws + ((wn * 64 + ni * 16 + l15) << 5) + (quad << 3));
#pragma unroll
    for (int mi = 0; mi < 4; ++mi)
#pragma unroll
      for (int ni = 0; ni < 4; ++ni)
        acc[mi][ni] = __builtin_amdgcn_mfma_f32_16x16x32_bf16(af[mi], wf[ni], acc[mi][ni], 0, 0, 0);
  }

#pragma unroll
  for (int ni = 0; ni < 4; ++ni) {
    const int n = bn + wn * 64 + ni * 16 + l15;
    const float bvb = bias[n];
#pragma unroll
    for (int mi = 0; mi < 4; ++mi) {
      const int m0 = bm + wm * 64 + mi * 16 + quad * 4;
      floatx4 v = acc[mi][ni];
#pragma unroll
      for (int r = 0; r < 4; ++r)
        out[(size_t)(m0 + r) * 1024 + n] = v[r] + bvb;
    }
  }
}

extern "C" void kernel_launch(void* const* d_in, const int* in_sizes, int n_in,
                              void* d_out, int out_size, void* d_ws, size_t ws_size,
                              hipStream_t stream) {
  const float* x  = (const float*)d_in[0];
  const float* Wq = (const float*)d_in[1];
  const float* bq = (const float*)d_in[2];
  const float* Wk = (const float*)d_in[3];
  const float* bk = (const float*)d_in[4];
  const float* Wv = (const float*)d_in[5];
  const float* bv = (const float*)d_in[6];
  const float* Wo = (const float*)d_in[7];
  const float* bo = (const float*)d_in[8];
  // d_in[9] = causal_mask (int32) — causality implemented analytically, unused.

  const size_t BUF = (size_t)B_ * NH_ * S_ * HD_;   // 8388608 elems
  __bf16* ws   = (__bf16*)d_ws;                     // ws usage: ~42 MB
  __bf16* xb   = ws;                                // 8388608  (16.8 MB)
  __bf16* Wcat = ws + 8388608;                      // 3145728  (6 MB)
  __bf16* Wob  = ws + 11534336;                     // 1048576  (2 MB)
  __bf16* Qb   = ws + 12582912;                     // 8388608  (16.8 MB)
  float*  bcat = (float*)(ws + 20971520);           // 3072 fp32 (12 KB)
  __bf16* Kb   = (__bf16*)d_out;                    // d_out reused as K+V^T
  __bf16* Vb   = (__bf16*)d_out + BUF;              // scratch until attn done

  dim3 blk(256);
  cvt_kernel<<<12291, blk, 0, stream>>>(x, Wq, Wk, Wv, Wo, bq, bk, bv,
                                        xb, Wcat, Wob, bcat);
  gemm_qkv_kernel<<<dim3(24, 64), blk, 0, stream>>>(xb, Wcat, bcat, Qb, Kb, Vb);
  attn_kernel<<<dim3(16, 64), blk, 0, stream>>>(Qb, Kb, Vb);
  gemm_o_kernel<<<dim3(8, 64), blk, 0, stream>>>(Qb, Wob, bo, (float*)d_out);
}

// Round 7
// 274.870 us; speedup vs baseline: 1.5175x; 1.0695x over previous
//
#include <hip/hip_runtime.h>
#include <hip/hip_bf16.h>

typedef __attribute__((ext_vector_type(8))) short short8;
typedef __attribute__((ext_vector_type(4))) float floatx4;

#define B_    4
#define S_    2048
#define EMB_  1024
#define NH_   16
#define HD_   64

#if __has_builtin(__builtin_amdgcn_exp2f)
#define EXP2F(x) __builtin_amdgcn_exp2f(x)
#else
#define EXP2F(x) exp2f(x)
#endif

__device__ __forceinline__ void async_cp16(const void* g, void* l) {
  __builtin_amdgcn_global_load_lds(
      (const __attribute__((address_space(1))) unsigned int*)g,
      (__attribute__((address_space(3))) unsigned int*)l, 16, 0, 0);
}

__device__ __forceinline__ ushort4 cvt4(const float4 f) {
  __bf16 t[4] = {(__bf16)f.x, (__bf16)f.y, (__bf16)f.z, (__bf16)f.w};
  return *(const ushort4*)t;
}

// One-shot fp32 -> bf16 conversion of x, Wq|Wk|Wv (stacked into Wcat), Wo,
// plus fp32 bias packing bq|bk|bv -> bcat. 4 elems/thread.
__global__ __launch_bounds__(256)
void cvt_kernel(const float* __restrict__ x,
                const float* __restrict__ wq, const float* __restrict__ wk,
                const float* __restrict__ wv, const float* __restrict__ wo,
                const float* __restrict__ bq, const float* __restrict__ bk,
                const float* __restrict__ bv,
                __bf16* __restrict__ xb, __bf16* __restrict__ Wcat,
                __bf16* __restrict__ Wob, float* __restrict__ bcat)
{
  const int NX4 = 2097152;   // 8388608/4
  const int NW4 = 262144;    // 1048576/4
  int g = blockIdx.x * 256 + threadIdx.x;
  if (g < NX4) {
    *(ushort4*)(xb + (size_t)g * 4) = cvt4(*(const float4*)(x + (size_t)g * 4));
    return;
  }
  g -= NX4;
  if (g < 3 * NW4) {   // Wcat = [Wq; Wk; Wv] row-stacked
    const float* src = (g < NW4) ? wq : (g < 2 * NW4) ? wk : wv;
    const int gg = (g < NW4) ? g : (g < 2 * NW4) ? g - NW4 : g - 2 * NW4;
    *(ushort4*)(Wcat + (size_t)g * 4) = cvt4(*(const float4*)(src + (size_t)gg * 4));
    return;
  }
  g -= 3 * NW4;
  if (g < NW4) {
    *(ushort4*)(Wob + (size_t)g * 4) = cvt4(*(const float4*)(wo + (size_t)g * 4));
    return;
  }
  g -= NW4;
  if (g < 768) {       // bcat = [bq; bk; bv] fp32
    const float* src = (g < 256) ? bq : (g < 512) ? bk : bv;
    *(float4*)(bcat + (size_t)g * 4) = *(const float4*)(src + (size_t)(g & 255) * 4);
  }
}

// Fused QKV: C[8192,3072] = xb @ Wcat^T + bcat, all bf16, global_load_lds staging.
// n<1024 -> Q (scaled by SCL*log2e) BHSD; n<2048 -> K BHSD; else -> V^T BHDS.
__global__ __launch_bounds__(256)
void gemm_qkv_kernel(const __bf16* __restrict__ A, const __bf16* __restrict__ W,
                     const float* __restrict__ bcat,
                     __bf16* __restrict__ Qb, __bf16* __restrict__ Kb,
                     __bf16* __restrict__ Vb)
{
  __shared__ __attribute__((aligned(16))) __bf16 As[128 * 32];
  __shared__ __attribute__((aligned(16))) __bf16 Ws[128 * 32];
  const int tid  = threadIdx.x;
  const int wave = tid >> 6, lane = tid & 63;
  const int l15  = lane & 15, quad = lane >> 4;
  const int wm   = wave >> 1, wn = wave & 1;
  const int bm   = blockIdx.y * 128;
  const int bn   = blockIdx.x * 128;        // 0..2944
  const int widx = bn >> 10;                // 0=Q 1=K 2=V (block-uniform)
  const float QS = 0.180336880f;            // (1/sqrt(64)) * log2(e)

  floatx4 acc[4][4];
#pragma unroll
  for (int i = 0; i < 4; ++i)
#pragma unroll
    for (int j = 0; j < 4; ++j) acc[i][j] = (floatx4){0.f, 0.f, 0.f, 0.f};

  const int srow = tid >> 2;          // 0..63
  const int scol = (tid & 3) << 3;    // 0,8,16,24
  const __bf16* Ag = A + (size_t)(bm + srow) * 1024 + scol;
  const __bf16* Wg = W + (size_t)(bn + srow) * 1024 + scol;
  __bf16* AsD = As + tid * 8;
  __bf16* WsD = Ws + tid * 8;

  for (int k0 = 0; k0 < 1024; k0 += 32) {
    __syncthreads();
    async_cp16(Ag + k0,             AsD);
    async_cp16(Ag + k0 + 64 * 1024, AsD + 2048);
    async_cp16(Wg + k0,             WsD);
    async_cp16(Wg + k0 + 64 * 1024, WsD + 2048);
    __syncthreads();
    short8 af[4], wf[4];
#pragma unroll
    for (int mi = 0; mi < 4; ++mi)
      af[mi] = *(const short8*)(As + ((wm * 64 + mi * 16 + l15) << 5) + (quad << 3));
#pragma unroll
    for (int ni = 0; ni < 4; ++ni)
      wf[ni] = *(const short8*)(Ws + ((wn * 64 + ni * 16 + l15) << 5) + (quad << 3));
#pragma unroll
    for (int mi = 0; mi < 4; ++mi)
#pragma unroll
      for (int ni = 0; ni < 4; ++ni)
        acc[mi][ni] = __builtin_amdgcn_mfma_f32_16x16x32_bf16(af[mi], wf[ni], acc[mi][ni], 0, 0, 0);
  }

#pragma unroll
  for (int ni = 0; ni < 4; ++ni) {
    const int n  = bn + wn * 64 + ni * 16 + l15;
    const float bvb = bcat[n];
    const int np = n & 1023;
    const int h = np >> 6, d = np & 63;
#pragma unroll
    for (int mi = 0; mi < 4; ++mi) {
      const int m0 = bm + wm * 64 + mi * 16 + quad * 4;
      const int b = m0 >> 11, s0 = m0 & 2047;
      floatx4 v = acc[mi][ni];
      if (widx == 0) {
        const size_t base = (size_t)(b * 16 + h) * (S_ * 64) + d;
#pragma unroll
        for (int r = 0; r < 4; ++r)
          Qb[base + (size_t)(s0 + r) * 64] = (__bf16)((v[r] + bvb) * QS);
      } else if (widx == 1) {
        const size_t base = (size_t)(b * 16 + h) * (S_ * 64) + d;
#pragma unroll
        for (int r = 0; r < 4; ++r)
          Kb[base + (size_t)(s0 + r) * 64] = (__bf16)(v[r] + bvb);
      } else {
        const size_t base = ((size_t)(b * 16 + h) * 64 + d) * S_ + s0;
        union { ushort4 u4; unsigned short u[4]; } pk;
#pragma unroll
        for (int r = 0; r < 4; ++r) {
          __bf16 hv = (__bf16)(v[r] + bvb);
          pk.u[r] = *(unsigned short*)&hv;
        }
        *(ushort4*)(Vb + base) = pk.u4;    // 8B aligned: s0 % 4 == 0
      }
    }
  }
}

// Online-softmax update for one 16-row q-group (lane owns q=l15, 16 k-values
// in s[ni][r], k = ksub*64 + ni*16 + quad*4 + r). T13 defer-max. tmax is
// cross-quad reduced (identical across the 4 quads of a q-row; also rescues
// all-masked quads).
__device__ __forceinline__ void softmax_update(
    floatx4* s, float& mrun, float& lsum, floatx4* oacc,
    __bf16* psbase, const int l15, const int quad)
{
  float t0 = fmaxf(fmaxf(s[0][0], s[0][1]), fmaxf(s[0][2], s[0][3]));
  float t1 = fmaxf(fmaxf(s[1][0], s[1][1]), fmaxf(s[1][2], s[1][3]));
  float t2 = fmaxf(fmaxf(s[2][0], s[2][1]), fmaxf(s[2][2], s[2][3]));
  float t3 = fmaxf(fmaxf(s[3][0], s[3][1]), fmaxf(s[3][2], s[3][3]));
  float tmax = fmaxf(fmaxf(t0, t1), fmaxf(t2, t3));
  tmax = fmaxf(tmax, __shfl_xor(tmax, 16));
  tmax = fmaxf(tmax, __shfl_xor(tmax, 32));

  const float mold = mrun;
  if (!__all(tmax <= mold + 8.0f)) {      // slow path: rescale
    const float mnew = fmaxf(mold, tmax);
    const float alpha = EXP2F(mold - mnew);
#pragma unroll
    for (int ni = 0; ni < 4; ++ni)
#pragma unroll
      for (int r = 0; r < 4; ++r) oacc[ni][r] *= alpha;
    lsum *= alpha;
    mrun = mnew;
  }
  const float m = mrun;
  float psum = 0.f;
#pragma unroll
  for (int ni = 0; ni < 4; ++ni) {
    float4 p;
    p.x = EXP2F(s[ni][0] - m);
    p.y = EXP2F(s[ni][1] - m);
    p.z = EXP2F(s[ni][2] - m);
    p.w = EXP2F(s[ni][3] - m);
    psum += (p.x + p.y) + (p.z + p.w);
    *(ushort4*)(psbase + l15 * 72 + ni * 16 + quad * 4) = cvt4(p);
  }
  lsum += psum;
}

// Flash attention, causal, exp2-domain (Q pre-scaled by SCL*log2e).
// 32 q-rows PER WAVE: each wave runs TWO 16-row groups (A: qw..qw+15,
// B: qw+16..qw+31) against SHARED K/V fragment reads -> LDS ops per 32 q-rows
// drop 52 -> 32 (K/V fragments were read redundantly per 16 rows; round-2 PMC
// accounting put the LDS pipe at ~74% -- the dominant stall).
// Block = 4 waves = 128 q-rows; grid (8, 64); serial pairing {qt, 15-qt}
// (36 sub-tiles/block, balanced); 2 blocks/CU. KVBLK=64, 16x16 MFMA engine,
// SWAPPED OPERANDS (S^T = mfma(K,Q), lane owns q-row = l15), lane-local
// softmax, T13 defer-max, per-wave Ps with wave-local lgkm drain, T14
// prefetch in NAMED scalars (uint4 arrays spill -- rounds 4/5).
// Wave-uniform compute-skip on the last diagonal sub-tile (waves 0/1).
// Output IN-PLACE over Q (block-owned rows). LDS 36 KB.
__global__ __launch_bounds__(256, 2)
void attn_kernel(__bf16* __restrict__ Q, const __bf16* __restrict__ K,
                 const __bf16* __restrict__ Vt)
{
  __shared__ __attribute__((aligned(16))) __bf16 Ks[64 * 72];      // [kv][d]
  __shared__ __attribute__((aligned(16))) __bf16 Vs[64 * 72];      // [d][kv]
  __shared__ __attribute__((aligned(16))) __bf16 Ps[4][2][16 * 72];

  const int tid  = threadIdx.x;
  const int wave = tid >> 6, lane = tid & 63;
  const int l15  = lane & 15, quad = lane >> 4;
  const int qtA  = blockIdx.x, bh = blockIdx.y;   // qtA in 0..7
  const size_t hb = (size_t)bh * (S_ * 64);
  const float MASKV = -1.0e30f;

  const int srow = tid >> 3;          // 0..31
  const int scol = (tid & 7) << 3;    // 0,8,...,56

  for (int qsel = 0; qsel < 2; ++qsel) {
    const int qt = qsel ? (15 - qtA) : qtA;   // 128-row q-tile index
    const int qw = qt * 128 + wave * 32;      // wave's first q row
    const int myqA = qw + l15;                // group A lane q row
    const int myqB = qw + 16 + l15;           // group B lane q row
    const int nsub = 2 * qt + 2;              // 64-kv sub-tiles to stage

    // Q fragments (B-operand view Q^T[c][q=l15]), named scalars
    const __bf16* qpA = Q + hb + (size_t)myqA * 64 + quad * 8;
    const __bf16* qpB = Q + hb + (size_t)myqB * 64 + quad * 8;
    short8 aqA0 = *(const short8*)(qpA);
    short8 aqA1 = *(const short8*)(qpA + 32);
    short8 aqB0 = *(const short8*)(qpB);
    short8 aqB1 = *(const short8*)(qpB + 32);

    floatx4 oaccA[4], oaccB[4];     // O^T: d = ni*16+quad*4+r, q = l15
#pragma unroll
    for (int j = 0; j < 4; ++j) {
      oaccA[j] = (floatx4){0.f, 0.f, 0.f, 0.f};
      oaccB[j] = (floatx4){0.f, 0.f, 0.f, 0.f};
    }
    float lsumA = 0.f, lsumB = 0.f;
    float mrunA = MASKV, mrunB = MASKV;

    // prologue: issue kt=0 tile loads into NAMED scalar regs (T14 issue-early)
    uint4 kreg0, kreg1, vreg0, vreg1;
    {
      const __bf16* kp = K  + hb + (size_t)srow * 64 + scol;
      const __bf16* vp = Vt + hb + (size_t)srow * S_ + scol;
      kreg0 = *(const uint4*)kp;
      kreg1 = *(const uint4*)(kp + 32 * 64);
      vreg0 = *(const uint4*)vp;
      vreg1 = *(const uint4*)(vp + (size_t)32 * S_);
    }

    for (int kt = 0; kt < nsub; ++kt) {
      __syncthreads();                      // all waves done reading prev tile
      *(uint4*)(&Ks[srow * 72 + scol])        = kreg0;
      *(uint4*)(&Ks[(srow + 32) * 72 + scol]) = kreg1;
      *(uint4*)(&Vs[srow * 72 + scol])        = vreg0;
      *(uint4*)(&Vs[(srow + 32) * 72 + scol]) = vreg1;
      __syncthreads();                      // tile staged

      if (kt + 1 < nsub) {                  // prefetch next 64-kv tile
        const __bf16* kp = K  + hb + (size_t)((kt + 1) * 64 + srow) * 64 + scol;
        const __bf16* vp = Vt + hb + (size_t)srow * S_ + (kt + 1) * 64 + scol;
        kreg0 = *(const uint4*)kp;
        kreg1 = *(const uint4*)(kp + 32 * 64);
        vreg0 = *(const uint4*)vp;
        vreg1 = *(const uint4*)(vp + (size_t)32 * S_);
      }

      if (kt * 64 <= qw + 31) {             // wave-uniform: any of my q needs this kt
        // S^T = K Q^T for BOTH groups; bk fragments read ONCE, shared.
        floatx4 sA[4], sB[4];
#pragma unroll
        for (int j = 0; j < 4; ++j) {
          sA[j] = (floatx4){0.f, 0.f, 0.f, 0.f};
          sB[j] = (floatx4){0.f, 0.f, 0.f, 0.f};
        }
#pragma unroll
        for (int kk = 0; kk < 2; ++kk) {
          const short8 aqa = kk ? aqA1 : aqA0;
          const short8 aqb = kk ? aqB1 : aqB0;
          short8 bk[4];
#pragma unroll
          for (int ni = 0; ni < 4; ++ni)
            bk[ni] = *(const short8*)(&Ks[(ni * 16 + l15) * 72 + kk * 32 + quad * 8]);
#pragma unroll
          for (int ni = 0; ni < 4; ++ni)
            sA[ni] = __builtin_amdgcn_mfma_f32_16x16x32_bf16(bk[ni], aqa, sA[ni], 0, 0, 0);
#pragma unroll
          for (int ni = 0; ni < 4; ++ni)
            sB[ni] = __builtin_amdgcn_mfma_f32_16x16x32_bf16(bk[ni], aqb, sB[ni], 0, 0, 0);
        }

        // causal masks (wave-uniform branch per group)
        const int kb = kt * 64 + quad * 4;
        if (kt * 64 + 63 > qw) {            // group A diagonal overlap
#pragma unroll
          for (int ni = 0; ni < 4; ++ni)
#pragma unroll
            for (int r = 0; r < 4; ++r)
              if (kb + ni * 16 + r > myqA) sA[ni][r] = MASKV;
        }
        if (kt * 64 + 63 > qw + 16) {       // group B diagonal overlap
#pragma unroll
          for (int ni = 0; ni < 4; ++ni)
#pragma unroll
            for (int r = 0; r < 4; ++r)
              if (kb + ni * 16 + r > myqB) sB[ni][r] = MASKV;
        }

        softmax_update(sA, mrunA, lsumA, oaccA, &Ps[wave][0][0], l15, quad);
        softmax_update(sB, mrunB, lsumB, oaccB, &Ps[wave][1][0], l15, quad);

        // Ps is per-wave: wave-local LDS drain instead of __syncthreads
        asm volatile("s_waitcnt lgkmcnt(0)" ::: "memory");
        __builtin_amdgcn_sched_barrier(0);

        // O^T += V^T P^T for BOTH groups; bv fragments read ONCE, shared.
#pragma unroll
        for (int kk = 0; kk < 2; ++kk) {
          short8 bv[4];
#pragma unroll
          for (int ni = 0; ni < 4; ++ni)
            bv[ni] = *(const short8*)(&Vs[(ni * 16 + l15) * 72 + kk * 32 + quad * 8]);
          const short8 pfA = *(const short8*)(&Ps[wave][0][l15 * 72 + kk * 32 + quad * 8]);
          const short8 pfB = *(const short8*)(&Ps[wave][1][l15 * 72 + kk * 32 + quad * 8]);
#pragma unroll
          for (int ni = 0; ni < 4; ++ni)
            oaccA[ni] = __builtin_amdgcn_mfma_f32_16x16x32_bf16(bv[ni], pfA, oaccA[ni], 0, 0, 0);
#pragma unroll
          for (int ni = 0; ni < 4; ++ni)
            oaccB[ni] = __builtin_amdgcn_mfma_f32_16x16x32_bf16(bv[ni], pfB, oaccB[ni], 0, 0, 0);
        }
      }
    }

    // epilogues: l(q) = sum over 4 quads of lane-local partials
    {
      float l = lsumA;
      l += __shfl_xor(l, 16);
      l += __shfl_xor(l, 32);
      const float inv = 1.0f / fmaxf(l, 1e-20f);
      const size_t rowb = hb + (size_t)myqA * 64;
#pragma unroll
      for (int ni = 0; ni < 4; ++ni) {
        float4 o;
        o.x = oaccA[ni][0] * inv;
        o.y = oaccA[ni][1] * inv;
        o.z = oaccA[ni][2] * inv;
        o.w = oaccA[ni][3] * inv;
        *(ushort4*)(Q + rowb + ni * 16 + quad * 4) = cvt4(o);  // 8B aligned
      }
    }
    {
      float l = lsumB;
      l += __shfl_xor(l, 16);
      l += __shfl_xor(l, 32);
      const float inv = 1.0f / fmaxf(l, 1e-20f);
      const size_t rowb = hb + (size_t)myqB * 64;
#pragma unroll
      for (int ni = 0; ni < 4; ++ni) {
        float4 o;
        o.x = oaccB[ni][0] * inv;
        o.y = oaccB[ni][1] * inv;
        o.z = oaccB[ni][2] * inv;
        o.w = oaccB[ni][3] * inv;
        *(ushort4*)(Q + rowb + ni * 16 + quad * 4) = cvt4(o);  // 8B aligned
      }
    }
  }
}

// Final projection: A = attn output (bf16, BHSD gather), W = Wob bf16,
// bias fp32, out fp32 row-major. global_load_lds staging.
__global__ __launch_bounds__(256)
void gemm_o_kernel(const __bf16* __restrict__ A, const __bf16* __restrict__ W,
                   const float* __restrict__ bias, float* __restrict__ out)
{
  __shared__ __attribute__((aligned(16))) __bf16 As[128 * 32];
  __shared__ __attribute__((aligned(16))) __bf16 Ws[128 * 32];
  const int tid  = threadIdx.x;
  const int wave = tid >> 6, lane = tid & 63;
  const int l15  = lane & 15, quad = lane >> 4;
  const int wm   = wave >> 1, wn = wave & 1;
  const int bm   = blockIdx.y * 128;
  const int bn   = blockIdx.x * 128;

  floatx4 acc[4][4];
#pragma unroll
  for (int i = 0; i < 4; ++i)
#pragma unroll
    for (int j = 0; j < 4; ++j) acc[i][j] = (floatx4){0.f, 0.f, 0.f, 0.f};

  const int srow = tid >> 2;
  const int scol = (tid & 3) << 3;
  const __bf16* Wg = W + (size_t)(bn + srow) * 1024 + scol;
  const int bb = bm >> 11;                 // batch
  const int ss = (bm & 2047) + srow;       // seq
  __bf16* AsD = As + tid * 8;
  __bf16* WsD = Ws + tid * 8;

  for (int k0 = 0; k0 < 1024; k0 += 32) {
    const int c = k0 + scol, h = c >> 6, dd = c & 63;  // 8 elems never cross a head
    const __bf16* pa0 = A + (((size_t)(bb * 16 + h) * S_) + ss) * 64 + dd;
    __syncthreads();
    async_cp16(pa0,           AsD);
    async_cp16(pa0 + 64 * 64, AsD + 2048);             // s -> s+64
    async_cp16(Wg + k0,             WsD);
    async_cp16(Wg + k0 + 64 * 1024, WsD + 2048);
    __syncthreads();

    short8 af[4], wf[4];
#pragma unroll
    for (int mi = 0; mi < 4; ++mi)
      af[mi] = *(const short8*)(As + ((wm * 64 + mi * 16 + l15) << 5) + (quad << 3));
#pragma unroll
    for (int ni = 0; ni < 4; ++ni)
      wf[ni] = *(const short8*)(Ws + ((wn * 64 + ni * 16 + l15) << 5) + (quad << 3));
#pragma unroll
    for (int mi = 0; mi < 4; ++mi)
#pragma unroll
      for (int ni = 0; ni < 4; ++ni)
        acc[mi][ni] = __builtin_amdgcn_mfma_f32_16x16x32_bf16(af[mi], wf[ni], acc[mi][ni], 0, 0, 0);
  }

#pragma unroll
  for (int ni = 0; ni < 4; ++ni) {
    const int n = bn + wn * 64 + ni * 16 + l15;
    const float bvb = bias[n];
#pragma unroll
    for (int mi = 0; mi < 4; ++mi) {
      const int m0 = bm + wm * 64 + mi * 16 + quad * 4;
      floatx4 v = acc[mi][ni];
#pragma unroll
      for (int r = 0; r < 4; ++r)
        out[(size_t)(m0 + r) * 1024 + n] = v[r] + bvb;
    }
  }
}

extern "C" void kernel_launch(void* const* d_in, const int* in_sizes, int n_in,
                              void* d_out, int out_size, void* d_ws, size_t ws_size,
                              hipStream_t stream) {
  const float* x  = (const float*)d_in[0];
  const float* Wq = (const float*)d_in[1];
  const float* bq = (const float*)d_in[2];
  const float* Wk = (const float*)d_in[3];
  const float* bk = (const float*)d_in[4];
  const float* Wv = (const float*)d_in[5];
  const float* bv = (const float*)d_in[6];
  const float* Wo = (const float*)d_in[7];
  const float* bo = (const float*)d_in[8];
  // d_in[9] = causal_mask (int32) — causality implemented analytically, unused.

  const size_t BUF = (size_t)B_ * NH_ * S_ * HD_;   // 8388608 elems
  __bf16* ws   = (__bf16*)d_ws;                     // ws usage: ~42 MB
  __bf16* xb   = ws;                                // 8388608  (16.8 MB)
  __bf16* Wcat = ws + 8388608;                      // 3145728  (6 MB)
  __bf16* Wob  = ws + 11534336;                     // 1048576  (2 MB)
  __bf16* Qb   = ws + 12582912;                     // 8388608  (16.8 MB)
  float*  bcat = (float*)(ws + 20971520);           // 3072 fp32 (12 KB)
  __bf16* Kb   = (__bf16*)d_out;                    // d_out reused as K+V^T
  __bf16* Vb   = (__bf16*)d_out + BUF;              // scratch until attn done

  dim3 blk(256);
  cvt_kernel<<<12291, blk, 0, stream>>>(x, Wq, Wk, Wv, Wo, bq, bk, bv,
                                        xb, Wcat, Wob, bcat);
  gemm_qkv_kernel<<<dim3(24, 64), blk, 0, stream>>>(xb, Wcat, bcat, Qb, Kb, Vb);
  attn_kernel<<<dim3(8, 64), blk, 0, stream>>>(Qb, Kb, Vb);
  gemm_o_kernel<<<dim3(8, 64), blk, 0, stream>>>(Qb, Wob, bo, (float*)d_out);
}